// Round 1
// 82.080 us; speedup vs baseline: 1.0781x; 1.0781x over previous
//
#include <hip/hip_runtime.h>
#include <math.h>

#define BLOCK 256

// Quotient-ring Horner step over F[l]/(l^3 - p l - q):
// (a0 + a1*l + a2*l^2) * l^2 + bn  ->  (q*a1 + bn, p*a1 + q*a2, a0 + p*a2)
#define QSTEP(a0, a1, a2, bn)                         \
    {                                                 \
        double n0 = fma(q, a1, bn);                   \
        double n1 = fma(p, a1, q * (a2));             \
        double n2 = fma(p, a2, a0);                   \
        a0 = n0; a1 = n1; a2 = n2;                    \
    }

__global__ __launch_bounds__(BLOCK) void lie_expm_kernel(const float* __restrict__ v,
                                                         float* __restrict__ out,
                                                         int n) {
    __shared__ float lds[BLOCK * 9];

    int tid = threadIdx.x;
    int gid = blockIdx.x * BLOCK + tid;
    bool active = gid < n;

    float oloc[9];

    if (active) {
        const float4* vv = reinterpret_cast<const float4*>(v);
        float4 p0 = vv[2 * (size_t)gid + 0];
        float4 p1 = vv[2 * (size_t)gid + 1];
        double x0 = p0.x, x1 = p0.y, x2 = p0.z, x3 = p0.w;
        double x4 = p1.x, x5 = p1.y, x6 = p1.z, x7 = p1.w;

        // A = sum_k v_k * G_k  (sl(3) basis -> A is traceless)
        double A[9];
        A[0] = x3 + x4;  A[1] = x5 - x2;  A[2] = x0;
        A[3] = x2 + x5;  A[4] = x3 - x4;  A[5] = x1;
        A[6] = x6;       A[7] = x7;       A[8] = -2.0 * x3;

        // 1-norm (max abs column sum)
        double c0 = fabs(A[0]) + fabs(A[3]) + fabs(A[6]);
        double c1 = fabs(A[1]) + fabs(A[4]) + fabs(A[7]);
        double c2 = fabs(A[2]) + fabs(A[5]) + fabs(A[8]);
        double nrm = fmax(c0, fmax(c1, c2));

        // Pade-13 theta (Higham 2005); branch-free exponent grab for s
        const double theta13 = 5.371920351148152;
        double r = nrm * (1.0 / theta13);
        int s = 0;
        if (r > 1.0) {
            int hi = __double2hiint(r);
            s = ((hi >> 20) & 0x7ff) - 1023 + 1;   // ceil(log2 r) (conservative)
        }
        double sc = __hiloint2double((1023 - s) << 20, 0);   // 2^-s
#pragma unroll
        for (int i = 0; i < 9; ++i) A[i] *= sc;

        // The ONLY matrix product: A2 = A*A (needed for final reconstruction,
        // and its diagonal gives tr(A^2) for free).
        double A2[9];
#pragma unroll
        for (int i = 0; i < 3; ++i) {
#pragma unroll
            for (int j = 0; j < 3; ++j) {
                A2[i * 3 + j] = fma(A[i * 3 + 0], A[0 * 3 + j],
                                fma(A[i * 3 + 1], A[1 * 3 + j],
                                    A[i * 3 + 2] * A[2 * 3 + j]));
            }
        }

        // Cayley-Hamilton for traceless 3x3: A^3 = p*A + q*I
        double p = 0.5 * (A2[0] + A2[4] + A2[8]);                 // tr(A^2)/2
        double q = fma(A[0], fma(A[4], A[8], -A[5] * A[7]),
                   fma(-A[1], fma(A[3], A[8], -A[5] * A[6]),
                       A[2] * fma(A[3], A[7], -A[4] * A[6])));    // det(A)

        // Pade-13 coefficients
        const double b0  = 64764752532480000.0, b1  = 32382376266240000.0;
        const double b2  = 7771770303897600.0,  b3  = 1187353796428800.0;
        const double b4  = 129060195264000.0,   b5  = 10559470521600.0;
        const double b6  = 670442572800.0,      b7  = 33522128640.0;
        const double b8  = 1323241920.0,        b9  = 40840800.0;
        const double b10 = 960960.0,            b11 = 16380.0;
        const double b12 = 182.0,               b13 = 1.0;

        // Scalar Horner in B = A^2 over F[l]/(l^3 - p l - q).
        // u-triple: sum b_{2k+1} B^k ; t-triple: sum b_{2k} B^k
        double u0 = b13, u1 = 0.0, u2 = 0.0;
        QSTEP(u0, u1, u2, b11)
        QSTEP(u0, u1, u2, b9)
        QSTEP(u0, u1, u2, b7)
        QSTEP(u0, u1, u2, b5)
        QSTEP(u0, u1, u2, b3)
        QSTEP(u0, u1, u2, b1)

        double t0 = b12, t1 = 0.0, t2 = 0.0;
        QSTEP(t0, t1, t2, b10)
        QSTEP(t0, t1, t2, b8)
        QSTEP(t0, t1, t2, b6)
        QSTEP(t0, t1, t2, b4)
        QSTEP(t0, t1, t2, b2)
        QSTEP(t0, t1, t2, b0)

        // U = A * (u0 I + u1 A + u2 A^2) reduced back into the basis
        double U0 = q * u2;
        double U1 = fma(p, u2, u0);
        double U2 = u1;

        // M = V - U, R = V + U (as triples)
        double m0 = t0 - U0, m1 = t1 - U1, m2 = t2 - U2;
        double r0 = t0 + U0, r1 = t1 + U1, r2 = t2 + U2;

        // Multiply-by-M operator in basis {I, A, A^2}
        double L00 = m0,              L01 = q * m2,          L02 = q * m1;
        double L10 = m1,              L11 = fma(p, m2, m0),  L12 = fma(p, m1, q * m2);
        double L20 = m2,              L21 = m1,              L22 = L11;

        // Adjugate of L
        double C00 = fma(L11, L22, -L12 * L21);
        double C01 = fma(L02, L21, -L01 * L22);
        double C02 = fma(L01, L12, -L02 * L11);
        double C10 = fma(L12, L20, -L10 * L22);
        double C11 = fma(L00, L22, -L02 * L20);
        double C12 = fma(L02, L10, -L00 * L12);
        double C20 = fma(L10, L21, -L11 * L20);
        double C21 = fma(L01, L20, -L00 * L21);
        double C22 = fma(L00, L11, -L01 * L10);

        // e = adj(L)*r = det(L) * (true Pade coefficients); the det(L) scalar
        // cancels in the final homogeneous normalization, so no divide here.
        double e0 = fma(C00, r0, fma(C01, r1, C02 * r2));
        double e1 = fma(C10, r0, fma(C11, r1, C12 * r2));
        double e2 = fma(C20, r0, fma(C21, r1, C22 * r2));

        // Overflow guard for the (essentially impossible) s >= 3 case
        // (requires ||A||_1 > 21.5): divide out det before squaring.
        if (s >= 3) {
            double det = fma(L00, C00, fma(L01, C10, L02 * C20));
            double rd = 1.0 / det;
            e0 *= rd; e1 *= rd; e2 *= rd;
        }

        // Undo scaling: square in the quotient ring (14 flops vs 45 for mm3)
        for (int i = 0; i < s; ++i) {
            double d0 = e0 * e0;
            double d1 = 2.0 * e0 * e1;
            double d2 = fma(e1, e1, 2.0 * e0 * e2);
            double d3 = 2.0 * e1 * e2;
            double d4 = e2 * e2;
            e0 = fma(q, d3, d0);
            e1 = fma(p, d3, fma(q, d4, d1));
            e2 = fma(p, d4, d2);
        }

        // H = e0 I + e1 A + e2 A^2  (scaled by det^(2^s); cancels below)
        double H[9];
#pragma unroll
        for (int i = 0; i < 9; ++i) H[i] = fma(e1, A[i], e2 * A2[i]);
        H[0] += e0; H[4] += e0; H[8] += e0;

        // Homogeneous normalization (absorbs all scalar factors)
        double invh = 1.0 / H[8];
#pragma unroll
        for (int i = 0; i < 9; ++i) oloc[i] = (float)(H[i] * invh);
    }

    // coalesced store via LDS: block covers BLOCK*9 contiguous floats
    if (active) {
#pragma unroll
        for (int j = 0; j < 9; ++j) lds[tid * 9 + j] = oloc[j];
    }
    __syncthreads();

    size_t base = (size_t)blockIdx.x * (BLOCK * 9);
    int count = n - blockIdx.x * BLOCK;
    if (count > BLOCK) count = BLOCK;
    int total = count * 9;
#pragma unroll
    for (int i = 0; i < 9; ++i) {
        int idx = i * BLOCK + tid;
        if (idx < total) out[base + idx] = lds[idx];
    }
}

extern "C" void kernel_launch(void* const* d_in, const int* in_sizes, int n_in,
                              void* d_out, int out_size, void* d_ws, size_t ws_size,
                              hipStream_t stream) {
    const float* v = (const float*)d_in[0];
    float* out = (float*)d_out;
    int n = in_sizes[0] / 8;   // B rows of 8 coefficients
    int grid = (n + BLOCK - 1) / BLOCK;
    lie_expm_kernel<<<grid, BLOCK, 0, stream>>>(v, out, n);
}

// Round 2
// 81.668 us; speedup vs baseline: 1.0836x; 1.0050x over previous
//
#include <hip/hip_runtime.h>
#include <math.h>

#define BLOCK 256

// Quotient-ring Horner step over F[l]/(l^3 - pp*l - qq):
// (a0 + a1*l + a2*l^2) * l^2 + bn  ->  (qq*a1 + bn, pp*a1 + qq*a2, a0 + pp*a2)
#define QSTEP(a0, a1, a2, bn)                         \
    {                                                 \
        double n0 = fma(qq, a1, bn);                  \
        double n1 = fma(pp, a1, qq * (a2));           \
        double n2 = fma(pp, a2, a0);                  \
        a0 = n0; a1 = n1; a2 = n2;                    \
    }

__global__ __launch_bounds__(BLOCK, 4) void lie_expm_kernel(const float* __restrict__ v,
                                                            float* __restrict__ out,
                                                            int n) {
    __shared__ float lds[BLOCK * 9];

    int tid = threadIdx.x;
    int gid = blockIdx.x * BLOCK + tid;
    bool active = gid < n;

    if (active) {
        const float4* vv = reinterpret_cast<const float4*>(v);
        float4 p0 = vv[2 * (size_t)gid + 0];
        float4 p1 = vv[2 * (size_t)gid + 1];

        // ---- s selection entirely in fp32, parallel to the fp64 chain ----
        // 1-norm (max abs column sum) of A, computed from raw inputs
        float c0f = fabsf(p0.w + p1.x) + fabsf(p0.z + p1.y) + fabsf(p1.z);
        float c1f = fabsf(p1.y - p0.z) + fabsf(p0.w - p1.x) + fabsf(p1.w);
        float c2f = fabsf(p0.x) + fabsf(p0.y) + 2.0f * fabsf(p0.w);
        float nrmf = fmaxf(c0f, fmaxf(c1f, c2f));
        const float inv_theta13 = (float)(1.0 / 5.371920351148152);
        float rf = nrmf * inv_theta13;
        int s = 0;
        if (rf > 1.0f) {
            int hi = __float_as_int(rf);
            s = ((hi >> 23) & 0xff) - 127 + 1;     // ceil(log2 r) (conservative)
            if (s > 60) s = 60;                     // paranoia clamp
        }
        // exact powers of two: 2^-s, 4^-s, 8^-s
        double sc1 = __hiloint2double((1023 - s)     << 20, 0);
        double sc2 = __hiloint2double((1023 - 2 * s) << 20, 0);
        double sc3 = __hiloint2double((1023 - 3 * s) << 20, 0);

        // ---- A (UNSCALED; scaling folded into invariants only) ----
        double x0 = p0.x, x1 = p0.y, x2 = p0.z, x3 = p0.w;
        double x4 = p1.x, x5 = p1.y, x6 = p1.z, x7 = p1.w;
        double A[9];
        A[0] = x3 + x4;  A[1] = x5 - x2;  A[2] = x0;
        A[3] = x2 + x5;  A[4] = x3 - x4;  A[5] = x1;
        A[6] = x6;       A[7] = x7;       A[8] = -2.0 * x3;

        // The ONLY matrix product: A2 = A*A (starts immediately, no wait on s)
        double A2[9];
#pragma unroll
        for (int i = 0; i < 3; ++i) {
#pragma unroll
            for (int j = 0; j < 3; ++j) {
                A2[i * 3 + j] = fma(A[i * 3 + 0], A[0 * 3 + j],
                                fma(A[i * 3 + 1], A[1 * 3 + j],
                                    A[i * 3 + 2] * A[2 * 3 + j]));
            }
        }

        // Cayley-Hamilton invariants of the SCALED matrix A/2^s:
        // pp = tr((A/2^s)^2)/2 = (tr(A^2)/2) * 4^-s ; qq = det(A) * 8^-s
        double pu = 0.5 * (A2[0] + A2[4] + A2[8]);
        double qu = fma(A[0], fma(A[4], A[8], -A[5] * A[7]),
                    fma(-A[1], fma(A[3], A[8], -A[5] * A[6]),
                        A[2] * fma(A[3], A[7], -A[4] * A[6])));
        double pp = pu * sc2;
        double qq = qu * sc3;

        // Pade-13 coefficients
        const double b0  = 64764752532480000.0, b1  = 32382376266240000.0;
        const double b2  = 7771770303897600.0,  b3  = 1187353796428800.0;
        const double b4  = 129060195264000.0,   b5  = 10559470521600.0;
        const double b6  = 670442572800.0,      b7  = 33522128640.0;
        const double b8  = 1323241920.0,        b9  = 40840800.0;
        const double b10 = 960960.0,            b11 = 16380.0;
        const double b12 = 182.0,               b13 = 1.0;

        // Scalar Horner in B = (A/2^s)^2 over the quotient ring (two
        // independent chains -> ILP)
        double u0 = b13, u1 = 0.0, u2 = 0.0;
        QSTEP(u0, u1, u2, b11)
        QSTEP(u0, u1, u2, b9)
        QSTEP(u0, u1, u2, b7)
        QSTEP(u0, u1, u2, b5)
        QSTEP(u0, u1, u2, b3)
        QSTEP(u0, u1, u2, b1)

        double t0 = b12, t1 = 0.0, t2 = 0.0;
        QSTEP(t0, t1, t2, b10)
        QSTEP(t0, t1, t2, b8)
        QSTEP(t0, t1, t2, b6)
        QSTEP(t0, t1, t2, b4)
        QSTEP(t0, t1, t2, b2)
        QSTEP(t0, t1, t2, b0)

        // U = Asc * (u-poly) reduced into the basis
        double U0 = qq * u2;
        double U1 = fma(pp, u2, u0);
        double U2 = u1;

        // M = V - U, R = V + U (triples)
        double a  = t0 - U0, bq = t1 - U1, c  = t2 - U2;
        double r0 = t0 + U0, r1 = t1 + U1, r2 = t2 + U2;

        // Multiply-by-M operator L in basis {I, l, l^2}:
        // L = [[a, qc, qb],[b, a+pc, pb+qc],[c, b, a+pc]]
        double qc = qq * c;
        double qb = qq * bq;
        double d  = fma(pp, c, a);
        double Le = fma(pp, bq, qc);
        // adj(L) with shared subexpressions; e = adj(L)*r (det left in -
        // it cancels in the homogeneous normalization)
        double ad = a * d;
        double fb = qb * bq;
        double c00 = fma(d, d, -Le * bq);
        double c01 = fb - qc * d;
        double c02 = fma(qc, Le, -qb * d);
        double c10 = fma(Le, c, -bq * d);
        double c11 = fma(-qb, c, ad);
        double c12 = fb - a * Le;
        double c20 = fma(bq, bq, -d * c);
        double c21 = fma(qc, c, -a * bq);
        double c22 = fma(-qc, bq, ad);

        double e0 = fma(c00, r0, fma(c01, r1, c02 * r2));
        double e1 = fma(c10, r0, fma(c11, r1, c12 * r2));
        double e2 = fma(c20, r0, fma(c21, r1, c22 * r2));

        // Overflow guard for the (essentially impossible) s >= 3 case
        if (s >= 3) {
            double det = fma(a, c00, fma(qc, c10, qb * c20));
            double rd = 1.0 / det;
            e0 *= rd; e1 *= rd; e2 *= rd;
        }

        // Undo scaling: square in the quotient ring (14 flops per step)
        for (int i = 0; i < s; ++i) {
            double d0 = e0 * e0;
            double d1 = 2.0 * e0 * e1;
            double d2 = fma(e1, e1, 2.0 * e0 * e2);
            double d3 = 2.0 * e1 * e2;
            double d4 = e2 * e2;
            e0 = fma(qq, d3, d0);
            e1 = fma(pp, d3, fma(qq, d4, d1));
            e2 = fma(pp, d4, d2);
        }

        // Map back to the UNSCALED basis: exp(A) = e0 I + (e1 2^-s) A + (e2 4^-s) A^2
        double e1s = e1 * sc1;
        double e2s = e2 * sc2;

        double H8 = fma(e1s, A[8], fma(e2s, A2[8], e0));
        // fast full-precision reciprocal (rcp + 2 Newton steps)
#if __has_builtin(__builtin_amdgcn_rcp)
        double invh = __builtin_amdgcn_rcp(H8);
        invh = fma(invh, fma(-H8, invh, 1.0), invh);
        invh = fma(invh, fma(-H8, invh, 1.0), invh);
#else
        double invh = 1.0 / H8;
#endif

#pragma unroll
        for (int i = 0; i < 8; ++i) {
            double Hi = fma(e1s, A[i], fma(e2s, A2[i], (i == 0 || i == 4) ? e0 : 0.0));
            lds[tid * 9 + i] = (float)(Hi * invh);
        }
        lds[tid * 9 + 8] = 1.0f;   // H[8]/H[8]
    }
    __syncthreads();

    // coalesced float4 store: block covers BLOCK*9 contiguous floats
    size_t base = (size_t)blockIdx.x * (BLOCK * 9);
    int count = n - blockIdx.x * BLOCK;
    if (count > BLOCK) count = BLOCK;
    int total = count * 9;
    int nf4 = total >> 2;
    float4* out4 = reinterpret_cast<float4*>(out + base);
    const float4* lds4 = reinterpret_cast<const float4*>(lds);
#pragma unroll
    for (int i = 0; i < 3; ++i) {
        int idx = i * BLOCK + tid;
        if (idx < nf4) out4[idx] = lds4[idx];
    }
    // tail (only possible in the last block when total % 4 != 0)
    int remstart = nf4 << 2;
    int ridx = remstart + tid;
    if (ridx < total) out[base + ridx] = lds[ridx];
}

extern "C" void kernel_launch(void* const* d_in, const int* in_sizes, int n_in,
                              void* d_out, int out_size, void* d_ws, size_t ws_size,
                              hipStream_t stream) {
    const float* v = (const float*)d_in[0];
    float* out = (float*)d_out;
    int n = in_sizes[0] / 8;   // B rows of 8 coefficients
    int grid = (n + BLOCK - 1) / BLOCK;
    lie_expm_kernel<<<grid, BLOCK, 0, stream>>>(v, out, n);
}